// Round 7
// baseline (286.574 us; speedup 1.0000x reference)
//
#include <hip/hip_runtime.h>

// MPS classifier, MI355X gfx950. Round 13: DUAL-CHAIN WAVES.
// r12 post-mortem: per-step phases (read 2100 LDS cyc / MFMA 1242 / VALU 1278)
// ADD to 3758 because the barrier locksteps all waves into the same phase;
// doubling waves/SIMD (22->44% occ) changed nothing. Fix: 8 waves x 512 thr,
// each wave owns fwd 16-col strip w AND bwd 16-row strip w — two independent
// chains in one instruction stream. b-MFMAs execute while epi-f VALU issues
// (separate pipes, no deps); chain-b reads cover chain-f lgkm waits. All
// per-CU traffic identical to r12; only the schedule changes.
// VGPR ~230 (32 stream uint4 + 16 acc v4f) -> 2 waves/SIMD; LDS 86.7 KB
// pins 1 WG/CU so the compiler targets the 256-reg budget (r11 lesson).

typedef _Float16 v8h __attribute__((ext_vector_type(8)));
typedef _Float16 h2  __attribute__((ext_vector_type(2)));
typedef float    v4f __attribute__((ext_vector_type(4)));

#define PI_HALF 1.5707963267948966f
#define SITE_U4 4096                 // uint4 per site: 2 planes * 32 frags * 64
#define TOFF_U4 (127*4096)           // bwd (transposed) half base, in uint4

union U4H8 { uint4 u; v8h h; };

__device__ __forceinline__ v4f mfma16h(uint4 a, uint4 b, v4f c){
  U4H8 ua, ub; ua.u = a; ub.u = b;
  return __builtin_amdgcn_mfma_f32_16x16x32_f16(ua.h, ub.h, c, 0, 0, 0);
}
__device__ __forceinline__ unsigned pack2h(float lo, float hi){
  h2 p; p[0] = (_Float16)lo; p[1] = (_Float16)hi;
  return __builtin_bit_cast(unsigned, p);
}
__device__ __forceinline__ unsigned short f16b(float v){
  return __builtin_bit_cast(unsigned short, (_Float16)v);
}

// ---------------------------------------------------------------------------
// Repack mid (fp32 [254][128][2][128]) — r10/r12 verbatim.
// Blocks 0..507   (sites 0..126)  -> fwd B-op frags [site][d][kt4][nt8][64]:
//   (lane,j) = mid[site][k=32kt+8(lane>>4)+j][d][n=16nt+(lane&15)]
// Blocks 508..1015 (sites 127..253)-> bwd A-op frags at TOFF [srel][d][am8][kt4][64]:
//   (lane,j) = mid[site][m=16am+(lane&15)][d][k=32kt+8(lane>>4)+j]
// ---------------------------------------------------------------------------
__global__ __launch_bounds__(256) void repack_mid(const float* __restrict__ mid,
                                                  unsigned short* __restrict__ wsB){
  const int bid = blockIdx.x;
  if (bid < 508){
    int idx  = bid * 256 + threadIdx.x;
    int lg   = idx & 15;
    int nt   = (idx >> 4) & 7;
    int kt   = (idx >> 7) & 3;
    int d    = (idx >> 9) & 1;
    int site = idx >> 10;            // 0..126
    int q    = lg >> 2;
    int n0   = 16*nt + 4*(lg & 3);
    const float* src = mid + ((size_t)(site*128 + 32*kt + 8*q)*2 + d)*128 + n0;
    float V[8][4];
    #pragma unroll
    for (int j = 0; j < 8; ++j){
      float4 a = *(const float4*)(src + (size_t)j*256);
      V[j][0]=a.x; V[j][1]=a.y; V[j][2]=a.z; V[j][3]=a.w;
    }
    uint4* dst = (uint4*)wsB + ((((size_t)site*2 + d)*4 + kt)*8 + nt)*64
               + 16*q + 4*(lg & 3);
    #pragma unroll
    for (int t = 0; t < 4; ++t){
      uint4 o;
      o.x = pack2h(V[0][t], V[1][t]);
      o.y = pack2h(V[2][t], V[3][t]);
      o.z = pack2h(V[4][t], V[5][t]);
      o.w = pack2h(V[6][t], V[7][t]);
      dst[t] = o;
    }
  } else {
    int idx  = (bid - 508) * 256 + threadIdx.x;
    int lg   = idx & 15;
    int kt   = (idx >> 4) & 3;
    int am   = (idx >> 6) & 7;
    int d    = (idx >> 9) & 1;
    int srel = idx >> 10;            // 0..126
    int site = 127 + srel;
    int q    = lg >> 2;
    int m0   = 16*am + 4*(lg & 3);
    int k0   = 32*kt + 8*q;
    uint4* dst = (uint4*)wsB + TOFF_U4
               + ((((size_t)srel*2 + d)*8 + am)*4 + kt)*64 + 16*q + 4*(lg & 3);
    #pragma unroll
    for (int mp = 0; mp < 4; ++mp){
      const float* src = mid + ((size_t)((site*128 + m0 + mp)*2) + d)*128 + k0;
      float4 a = *(const float4*)(src);
      float4 b = *(const float4*)(src + 4);
      uint4 o;
      o.x = pack2h(a.x, a.y);
      o.y = pack2h(a.z, a.w);
      o.z = pack2h(b.x, b.y);
      o.w = pack2h(b.z, b.w);
      dst[mp] = o;
    }
  }
}

// ---------------------------------------------------------------------------
// Main kernel: 256 WGs x 512 threads (8 waves), 32 rows/WG, 1 WG/CU.
// Wave w: fwd cols [16w,16w+16) of left' AND bwd rows [16w,16w+16) of R.
// LDS: phiT[256][36] packed f16; Af/Rf state dbufs 16 KB each; Rcomb; scal.
// Slot swizzle: phys = S ^ ((S>>3)&7) on both write and read.
// ---------------------------------------------------------------------------
__global__ __launch_bounds__(512, 2) void mps_main(
    const float* __restrict__ x,               // [8192][256]
    const float* __restrict__ first,           // [2][128]
    const unsigned short* __restrict__ wsBv,   // repacked mid frags
    const float* __restrict__ lastw,           // [128][2]
    const float* __restrict__ wlin,            // [10]
    const float* __restrict__ blin,            // [10]
    float* __restrict__ out)                   // [8192][10]
{
  __shared__ unsigned phiT[256*36];        // 36 KB
  __shared__ unsigned Af[2*8*64*4];        // 16 KB [buf][frag=mt*4+kt][slot][word]
  __shared__ unsigned Rf[2*8*64*4];        // 16 KB [buf][frag=kt*2+nt][slot][word]
  __shared__ float Rcomb[128*33];          // 16.9 KB
  __shared__ float scal[32];

  const int tid  = threadIdx.x;
  const int gblk = blockIdx.x;
  const int w    = tid >> 6;               // wave 0..7
  const int lane = tid & 63;
  const int r    = lane & 15;
  const int q    = lane >> 4;
  const int rh   = r >> 3;
  const int rowbase = gblk * 32;
  const int physL = lane ^ ((lane >> 3) & 7);

  // ---- Phase 1: feature map -> packed f16 (cos,sin) table (all 256 sites) ----
  {
    const int row = tid >> 4;              // 0..31
    const int c0  = (tid & 15) * 16;       // 16-site chunk
    const float4* xp = (const float4*)(x + (size_t)(rowbase + row) * 256 + c0);
    float xv[16];
    float vmin = 3.0e38f, vmax = -3.0e38f;
    #pragma unroll
    for (int c = 0; c < 4; ++c){
      float4 u = xp[c];
      xv[c*4+0] = u.x; xv[c*4+1] = u.y; xv[c*4+2] = u.z; xv[c*4+3] = u.w;
      vmin = fminf(vmin, fminf(fminf(u.x,u.y), fminf(u.z,u.w)));
      vmax = fmaxf(vmax, fmaxf(fmaxf(u.x,u.y), fmaxf(u.z,u.w)));
    }
    #pragma unroll
    for (int m = 1; m < 16; m <<= 1){
      vmin = fminf(vmin, __shfl_xor(vmin, m));
      vmax = fmaxf(vmax, __shfl_xor(vmax, m));
    }
    const float sc = PI_HALF / (vmax - vmin + 1e-6f);
    #pragma unroll
    for (int j = 0; j < 16; ++j){
      float a = (xv[j] - vmin) * sc;
      phiT[(c0 + j)*36 + row] = pack2h(__cosf(a), __sinf(a));
    }
  }
  __syncthreads();

  // ---- State init (buf 0): every wave writes one Af frag AND one Rf frag ----
  {
    // fwd: L1[b][l] = c0(b)*first0[l] + s0(b)*first1[l]; frag (mt=w>>2, kt=w&3)
    const int mt = w >> 2, kt = w & 3;
    float f0[8], f1[8];
    #pragma unroll
    for (int j = 0; j < 8; ++j){
      int l = 32*kt + 8*q + j;
      f0[j] = first[l]; f1[j] = first[128 + l];
    }
    h2 p0 = __builtin_bit_cast(h2, phiT[0*36 + 16*mt + r]);
    const float c0 = (float)p0[0], s0 = (float)p0[1];
    uint4 o;
    o.x = pack2h(f0[0]*c0 + f1[0]*s0, f0[1]*c0 + f1[1]*s0);
    o.y = pack2h(f0[2]*c0 + f1[2]*s0, f0[3]*c0 + f1[3]*s0);
    o.z = pack2h(f0[4]*c0 + f1[4]*s0, f0[5]*c0 + f1[5]*s0);
    o.w = pack2h(f0[6]*c0 + f1[6]*s0, f0[7]*c0 + f1[7]*s0);
    *(uint4*)&Af[((mt*4 + kt)*64 + physL)*4] = o;
  }
  {
    // bwd: R254[k][b] = lastw[k][0]*c255(b) + lastw[k][1]*s255(b); frag (kt=w>>1, nt=w&1)
    const int kt = w >> 1, nt = w & 1;
    const int n  = 16*nt + r;
    h2 p5 = __builtin_bit_cast(h2, phiT[255*36 + n]);
    const float cb = (float)p5[0], sb = (float)p5[1];
    uint4 o; unsigned ow[4];
    #pragma unroll
    for (int jp = 0; jp < 4; ++jp){
      const int k = 32*kt + 8*q + 2*jp;
      float2 g0 = *(const float2*)(lastw + 2*k);
      float2 g1 = *(const float2*)(lastw + 2*(k+1));
      ow[jp] = pack2h(g0.x*cb + g0.y*sb, g1.x*cb + g1.y*sb);
    }
    o.x=ow[0]; o.y=ow[1]; o.z=ow[2]; o.w=ow[3];
    *(uint4*)&Rf[((kt*2 + nt)*64 + physL)*4] = o;
  }

  // ---- Step-0 stream prefetch (fwd site 0, bwd srel 126) ----
  uint4 Ff0[8], Ff1[8], Fb0[8], Fb1[8];    // [pl*4 + kt]
  {
    const uint4* bp = (const uint4*)wsBv;
    #pragma unroll
    for (int d = 0; d < 2; ++d)
      #pragma unroll
      for (int kk = 0; kk < 4; ++kk)
        Ff0[d*4+kk] = bp[(size_t)((d*4 + kk)*8 + w)*64 + lane];
  }
  {
    const uint4* bp = (const uint4*)wsBv + TOFF_U4 + (size_t)126 * SITE_U4;
    #pragma unroll
    for (int d = 0; d < 2; ++d)
      #pragma unroll
      for (int kk = 0; kk < 4; ++kk)
        Fb0[d*4+kk] = bp[(size_t)((d*8 + w)*4 + kk)*64 + lane];
  }

  // ---- Step body: fwd consumes mid[t] + phi(t+1); bwd mid[253-t] + phi(254-t) ----
  auto body = [&](int t, uint4 (&FfC)[8], uint4 (&FfN)[8],
                         uint4 (&FbC)[8], uint4 (&FbN)[8]){
    __syncthreads();   // state frags for step t visible; prev-buf reads done

    // prefetch fwd B for step t+1
    {
      const int soff = (t < 126) ? (t + 1) : 0;
      const uint4* bp = (const uint4*)wsBv + (size_t)soff * SITE_U4;
      #pragma unroll
      for (int d = 0; d < 2; ++d)
        #pragma unroll
        for (int kk = 0; kk < 4; ++kk)
          FfN[d*4+kk] = bp[(size_t)((d*4 + kk)*8 + w)*64 + lane];
    }
    // prefetch bwd A for step t+1
    {
      const int srel = (t < 126) ? (125 - t) : 0;
      const uint4* bp = (const uint4*)wsBv + TOFF_U4 + (size_t)srel * SITE_U4;
      #pragma unroll
      for (int d = 0; d < 2; ++d)
        #pragma unroll
        for (int kk = 0; kk < 4; ++kk)
          FbN[d*4+kk] = bp[(size_t)((d*8 + w)*4 + kk)*64 + lane];
    }

    // fwd chain MFMAs: rows 16mt+4q+reg, col l = 16w+r
    v4f fa0[2] = {};   // plane 0, [mt]
    v4f fa1[2] = {};   // plane 1, [mt]
    {
      const unsigned* Ab = &Af[(t & 1) * 2048];
      #pragma unroll
      for (int kt = 0; kt < 4; ++kt){
        uint4 a0 = *(const uint4*)&Ab[((0*4 + kt)*64 + physL)*4];
        uint4 a1 = *(const uint4*)&Ab[((1*4 + kt)*64 + physL)*4];
        fa0[0] = mfma16h(a0, FfC[0*4+kt], fa0[0]);
        fa0[1] = mfma16h(a1, FfC[0*4+kt], fa0[1]);
        fa1[0] = mfma16h(a0, FfC[1*4+kt], fa1[0]);
        fa1[1] = mfma16h(a1, FfC[1*4+kt], fa1[1]);
      }
    }
    // bwd chain MFMAs: rows k = 16w+4q+reg, col b = 16nt+r
    v4f ba0[2] = {};   // plane 0, [nt]
    v4f ba1[2] = {};   // plane 1, [nt]
    {
      const unsigned* Rb = &Rf[(t & 1) * 2048];
      #pragma unroll
      for (int kt = 0; kt < 4; ++kt){
        uint4 b0 = *(const uint4*)&Rb[((kt*2 + 0)*64 + physL)*4];
        uint4 b1 = *(const uint4*)&Rb[((kt*2 + 1)*64 + physL)*4];
        ba0[0] = mfma16h(FbC[0*4+kt], b0, ba0[0]);
        ba0[1] = mfma16h(FbC[0*4+kt], b1, ba0[1]);
        ba1[0] = mfma16h(FbC[1*4+kt], b0, ba1[0]);
        ba1[1] = mfma16h(FbC[1*4+kt], b1, ba1[1]);
      }
    }

    if (t < 126){
      // fwd epilogue: left'[b=16mt+4q+reg][l=16w+r] -> Af[(t+1)&1], frag (mt, w>>1)
      {
        unsigned short* Wb = (unsigned short*)&Af[((t+1) & 1) * 2048];
        const int X  = 4*(w & 1) + 2*rh + (q >> 1);
        const int S0 = 32*(w & 1) + 16*rh + 4*q;
        #pragma unroll
        for (int mt = 0; mt < 2; ++mt){
          uint4 phiu = *(const uint4*)&phiT[(t+1)*36 + 16*mt + 4*q];
          const unsigned pr[4] = {phiu.x, phiu.y, phiu.z, phiu.w};
          const int base16 = (mt*4 + (w >> 1))*512;
          #pragma unroll
          for (int reg = 0; reg < 4; ++reg){
            h2 ph = __builtin_bit_cast(h2, pr[reg]);
            float v = (float)ph[0]*fa0[mt][reg] + (float)ph[1]*fa1[mt][reg];
            Wb[base16 + ((S0 + reg) ^ X)*8 + (r & 7)] = f16b(v);
          }
        }
      }
      // bwd epilogue: R'[k=16w+4q+reg][b=16nt+r] -> Rf[(t+1)&1], frag (w>>1, nt)
      {
        const int ps = 254 - t;
        unsigned short* Wr = (unsigned short*)&Rf[((t+1) & 1) * 2048];
        const int X = 4*(w & 1) + 2*(q >> 1) + rh;
        const int S = (32*(w & 1) + 16*(q >> 1) + r) ^ X;
        #pragma unroll
        for (int nt = 0; nt < 2; ++nt){
          h2 ph = __builtin_bit_cast(h2, phiT[ps*36 + 16*nt + r]);
          const float cb = (float)ph[0], sb = (float)ph[1];
          const int base = ((w >> 1)*2 + nt)*512 + S*8 + 4*(q & 1);
          #pragma unroll
          for (int reg = 0; reg < 4; ++reg){
            float v = cb*ba0[nt][reg] + sb*ba1[nt][reg];
            Wr[base + reg] = f16b(v);
          }
        }
      }
    } else {
      // fwd final: vf = left_128 rows (phi 127 applied), held in registers
      float vf[2][4];
      #pragma unroll
      for (int mt = 0; mt < 2; ++mt){
        uint4 phiu = *(const uint4*)&phiT[127*36 + 16*mt + 4*q];
        const unsigned pr[4] = {phiu.x, phiu.y, phiu.z, phiu.w};
        #pragma unroll
        for (int reg = 0; reg < 4; ++reg){
          h2 ph = __builtin_bit_cast(h2, pr[reg]);
          vf[mt][reg] = (float)ph[0]*fa0[mt][reg] + (float)ph[1]*fa1[mt][reg];
        }
      }
      // bwd final: R_127 (phi 128 applied) -> Rcomb[l][b]
      #pragma unroll
      for (int nt = 0; nt < 2; ++nt){
        h2 ph = __builtin_bit_cast(h2, phiT[128*36 + 16*nt + r]);
        const float cb = (float)ph[0], sb = (float)ph[1];
        #pragma unroll
        for (int reg = 0; reg < 4; ++reg){
          float v = cb*ba0[nt][reg] + sb*ba1[nt][reg];
          const int l = 16*w + 4*q + reg;
          Rcomb[l*33 + 16*nt + r] = v;
        }
      }
      if (tid < 32) scal[tid] = 0.0f;
      __syncthreads();   // Rcomb + scal ready (uniform barrier)

      // combine: scalar[b] += sum over this wave's 16 cols
      float p[2][4];
      const int lcol = 16*w + r;
      #pragma unroll
      for (int mt = 0; mt < 2; ++mt)
        #pragma unroll
        for (int reg = 0; reg < 4; ++reg)
          p[mt][reg] = vf[mt][reg] * Rcomb[lcol*33 + 16*mt + 4*q + reg];
      #pragma unroll
      for (int m = 1; m < 16; m <<= 1)
        #pragma unroll
        for (int mt = 0; mt < 2; ++mt)
          #pragma unroll
          for (int reg = 0; reg < 4; ++reg)
            p[mt][reg] += __shfl_xor(p[mt][reg], m);
      if (r == 0){
        #pragma unroll
        for (int mt = 0; mt < 2; ++mt)
          #pragma unroll
          for (int reg = 0; reg < 4; ++reg)
            atomicAdd(&scal[16*mt + 4*q + reg], p[mt][reg]);
      }
      __syncthreads();
      for (int t2 = tid; t2 < 320; t2 += 512){
        int bb = t2 / 10, o = t2 - bb*10;
        out[(size_t)(rowbase + bb)*10 + o] = scal[bb]*wlin[o] + blin[o];
      }
    }
  };

  #pragma unroll 1
  for (int t = 0; t < 126; t += 2){
    body(t,     Ff0, Ff1, Fb0, Fb1);
    body(t + 1, Ff1, Ff0, Fb1, Fb0);
  }
  body(126, Ff0, Ff1, Fb0, Fb1);
}

extern "C" void kernel_launch(void* const* d_in, const int* in_sizes, int n_in,
                              void* d_out, int out_size, void* d_ws, size_t ws_size,
                              hipStream_t stream){
  (void)in_sizes; (void)n_in; (void)out_size; (void)ws_size;
  const float* x     = (const float*)d_in[0];
  const float* first = (const float*)d_in[1];
  const float* mid   = (const float*)d_in[2];
  const float* lastw = (const float*)d_in[3];
  const float* wlin  = (const float*)d_in[4];
  const float* blin  = (const float*)d_in[5];
  float* o            = (float*)d_out;
  unsigned short* wsB = (unsigned short*)d_ws;   // 16.6 MB fp16 fragments

  hipLaunchKernelGGL(repack_mid, dim3(1016), dim3(256), 0, stream, mid, wsB);
  hipLaunchKernelGGL(mps_main,   dim3(256),  dim3(512), 0, stream,
                     x, first, wsB, lastw, wlin, blin, o);
}

// Round 8
// 277.024 us; speedup vs baseline: 1.0345x; 1.0345x over previous
//
#include <hip/hip_runtime.h>

// MPS classifier, MI355X gfx950. Round 14: r9 structure + COUNTED WAITS
// ACROSS RAW BARRIERS. r13 post-mortem: __syncthreads() emits
// s_waitcnt vmcnt(0) before s_barrier -> every step drains the B-stream
// prefetch; L2/L3 RTT exposed per step in ALL variants (the 5-round
// invariant). Fix (T4): per-step sync = s_waitcnt lgkmcnt(0) (LDS only)
// + raw s_barrier + sched_barrier fences. Global loads stay in flight
// across the barrier; compiler emits counted vmcnt before first use.
// Structure = r9 (best, 189us): waves 0-3 fwd / 4-7 bwd in one WG,
// state dbufs in LDS, B-stream in registers. Repack = r12's half-size
// (fwd format sites 0..126 only, bwd-T format sites 127..253 only).

typedef _Float16 v8h __attribute__((ext_vector_type(8)));
typedef _Float16 h2  __attribute__((ext_vector_type(2)));
typedef float    v4f __attribute__((ext_vector_type(4)));

#define PI_HALF 1.5707963267948966f
#define SITE_U4 4096                 // uint4 per site: 2 planes * 32 frags * 64
#define TOFF_U4 (127*4096)           // bwd (transposed) half base, in uint4

union U4H8 { uint4 u; v8h h; };

__device__ __forceinline__ v4f mfma16h(uint4 a, uint4 b, v4f c){
  U4H8 ua, ub; ua.u = a; ub.u = b;
  return __builtin_amdgcn_mfma_f32_16x16x32_f16(ua.h, ub.h, c, 0, 0, 0);
}
__device__ __forceinline__ unsigned pack2h(float lo, float hi){
  h2 p; p[0] = (_Float16)lo; p[1] = (_Float16)hi;
  return __builtin_bit_cast(unsigned, p);
}
__device__ __forceinline__ unsigned short f16b(float v){
  return __builtin_bit_cast(unsigned short, (_Float16)v);
}

// step-boundary sync: drain LDS ops only, raw barrier (NO vmcnt drain),
// fence the scheduler so DS reads don't hoist above the barrier.
__device__ __forceinline__ void step_sync(){
  __builtin_amdgcn_sched_barrier(0);
  asm volatile("s_waitcnt lgkmcnt(0)" ::: "memory");
  __builtin_amdgcn_s_barrier();
  __builtin_amdgcn_sched_barrier(0);
}

// ---------------------------------------------------------------------------
// Repack mid (fp32 [254][128][2][128]) — half-size (r12 verbatim).
// Blocks 0..507   (sites 0..126)  -> fwd B-op frags [site][d][kt4][nt8][64]:
//   (lane,j) = mid[site][k=32kt+8(lane>>4)+j][d][n=16nt+(lane&15)]
// Blocks 508..1015 (sites 127..253)-> bwd A-op frags at TOFF [srel][d][am8][kt4][64]:
//   (lane,j) = mid[site][m=16am+(lane&15)][d][k=32kt+8(lane>>4)+j]
// ---------------------------------------------------------------------------
__global__ __launch_bounds__(256) void repack_mid(const float* __restrict__ mid,
                                                  unsigned short* __restrict__ wsB){
  const int bid = blockIdx.x;
  if (bid < 508){
    int idx  = bid * 256 + threadIdx.x;
    int lg   = idx & 15;
    int nt   = (idx >> 4) & 7;
    int kt   = (idx >> 7) & 3;
    int d    = (idx >> 9) & 1;
    int site = idx >> 10;            // 0..126
    int q    = lg >> 2;
    int n0   = 16*nt + 4*(lg & 3);
    const float* src = mid + ((size_t)(site*128 + 32*kt + 8*q)*2 + d)*128 + n0;
    float V[8][4];
    #pragma unroll
    for (int j = 0; j < 8; ++j){
      float4 a = *(const float4*)(src + (size_t)j*256);
      V[j][0]=a.x; V[j][1]=a.y; V[j][2]=a.z; V[j][3]=a.w;
    }
    uint4* dst = (uint4*)wsB + ((((size_t)site*2 + d)*4 + kt)*8 + nt)*64
               + 16*q + 4*(lg & 3);
    #pragma unroll
    for (int t = 0; t < 4; ++t){
      uint4 o;
      o.x = pack2h(V[0][t], V[1][t]);
      o.y = pack2h(V[2][t], V[3][t]);
      o.z = pack2h(V[4][t], V[5][t]);
      o.w = pack2h(V[6][t], V[7][t]);
      dst[t] = o;
    }
  } else {
    int idx  = (bid - 508) * 256 + threadIdx.x;
    int lg   = idx & 15;
    int kt   = (idx >> 4) & 3;
    int am   = (idx >> 6) & 7;
    int d    = (idx >> 9) & 1;
    int srel = idx >> 10;            // 0..126
    int site = 127 + srel;
    int q    = lg >> 2;
    int m0   = 16*am + 4*(lg & 3);
    int k0   = 32*kt + 8*q;
    uint4* dst = (uint4*)wsB + TOFF_U4
               + ((((size_t)srel*2 + d)*8 + am)*4 + kt)*64 + 16*q + 4*(lg & 3);
    #pragma unroll
    for (int mp = 0; mp < 4; ++mp){
      const float* src = mid + ((size_t)((site*128 + m0 + mp)*2) + d)*128 + k0;
      float4 a = *(const float4*)(src);
      float4 b = *(const float4*)(src + 4);
      uint4 o;
      o.x = pack2h(a.x, a.y);
      o.y = pack2h(a.z, a.w);
      o.z = pack2h(b.x, b.y);
      o.w = pack2h(b.z, b.w);
      dst[mp] = o;
    }
  }
}

// ---------------------------------------------------------------------------
// Main kernel (r9 structure). 256 WGs x 512 threads, 32 rows/WG.
// Waves 0-3 fwd (left' = c*(L@M0)+s*(L@M1), state = A-op in LDS);
// waves 4-7 bwd (R' = c*(M0@R)+s*(M1@R), state = B-op in LDS, stream = A-op-T).
// Middle combine in-WG: scalar[b] = sum_l L128[b,l]*R127[l,b].
// Slot swizzle: phys = S ^ ((S>>3)&7) on write and read.
// ---------------------------------------------------------------------------
__global__ __launch_bounds__(512, 2) void mps_main(
    const float* __restrict__ x,               // [8192][256]
    const float* __restrict__ first,           // [2][128]
    const unsigned short* __restrict__ wsBv,   // repacked mid (both halves)
    const float* __restrict__ lastw,           // [128][2]
    const float* __restrict__ wlin,            // [10]
    const float* __restrict__ blin,            // [10]
    float* __restrict__ out)                   // [8192][10]
{
  __shared__ unsigned phiT[256*36];        // 36 KB
  __shared__ unsigned Af[2*2*4*64*4];      // 16 KB  [buf][mt][kt][slot][word]
  __shared__ unsigned Rf[2*4*2*64*4];      // 16 KB  [buf][kt][nt][slot][word]
  __shared__ float Rcomb[128*33];          // 16.9 KB
  __shared__ float scal[32];

  const int tid  = threadIdx.x;
  const int gblk = blockIdx.x;
  const int w    = tid >> 6;               // 0..3 fwd, 4..7 bwd
  const int lane = tid & 63;
  const int r    = lane & 15;
  const int q    = lane >> 4;
  const int rh   = r >> 3;
  const int rowbase = gblk * 32;
  const int physL = lane ^ ((lane >> 3) & 7);

  // ---- Phase 1: feature map -> packed f16 (cos,sin) table ----
  {
    const int row = tid >> 4;              // 0..31
    const int c0  = (tid & 15) * 16;       // 16-site chunk
    const float4* xp = (const float4*)(x + (size_t)(rowbase + row) * 256 + c0);
    float xv[16];
    float vmin = 3.0e38f, vmax = -3.0e38f;
    #pragma unroll
    for (int c = 0; c < 4; ++c){
      float4 u = xp[c];
      xv[c*4+0] = u.x; xv[c*4+1] = u.y; xv[c*4+2] = u.z; xv[c*4+3] = u.w;
      vmin = fminf(vmin, fminf(fminf(u.x,u.y), fminf(u.z,u.w)));
      vmax = fmaxf(vmax, fmaxf(fmaxf(u.x,u.y), fmaxf(u.z,u.w)));
    }
    #pragma unroll
    for (int m = 1; m < 16; m <<= 1){
      vmin = fminf(vmin, __shfl_xor(vmin, m));
      vmax = fmaxf(vmax, __shfl_xor(vmax, m));
    }
    const float sc = PI_HALF / (vmax - vmin + 1e-6f);
    #pragma unroll
    for (int j = 0; j < 16; ++j){
      float a = (xv[j] - vmin) * sc;
      phiT[(c0 + j)*36 + row] = pack2h(__cosf(a), __sinf(a));
    }
  }
  __syncthreads();

  // ---- Initial B prefetch (step 0): fwd site 0, bwd srel 126 (site 253) ----
  uint4 B0[16], B1[16];
  if (w < 4){
    const uint4* bp = (const uint4*)wsBv;
    #pragma unroll
    for (int d = 0; d < 2; ++d)
      #pragma unroll
      for (int kt = 0; kt < 4; ++kt)
        #pragma unroll
        for (int nb = 0; nb < 2; ++nb)
          B0[(d*4+kt)*2+nb] = bp[(size_t)((d*4 + kt)*8 + 2*w + nb)*64 + lane];
  } else {
    const int ww = w - 4;
    const uint4* bp = (const uint4*)wsBv + TOFF_U4 + (size_t)126 * SITE_U4;
    #pragma unroll
    for (int d = 0; d < 2; ++d)
      #pragma unroll
      for (int mtl = 0; mtl < 2; ++mtl)
        #pragma unroll
        for (int kt = 0; kt < 4; ++kt)
          B0[(d*2+mtl)*4+kt] = bp[(size_t)((d*8 + 2*ww + mtl)*4 + kt)*64 + lane];
  }

  // ---- State init (buf 0) ----
  if (w < 4){
    // left_1[b][l] = c0(b)*first[0][l] + s0(b)*first[1][l]; wave w: kt=w
    float f0[8], f1[8];
    #pragma unroll
    for (int j = 0; j < 8; ++j){
      int l = 32*w + 8*q + j;
      f0[j] = first[l]; f1[j] = first[128 + l];
    }
    #pragma unroll
    for (int mt = 0; mt < 2; ++mt){
      h2 ph0 = __builtin_bit_cast(h2, phiT[0*36 + 16*mt + r]);
      const float c0 = (float)ph0[0], s0 = (float)ph0[1];
      uint4 o;
      o.x = pack2h(f0[0]*c0 + f1[0]*s0, f0[1]*c0 + f1[1]*s0);
      o.y = pack2h(f0[2]*c0 + f1[2]*s0, f0[3]*c0 + f1[3]*s0);
      o.z = pack2h(f0[4]*c0 + f1[4]*s0, f0[5]*c0 + f1[5]*s0);
      o.w = pack2h(f0[6]*c0 + f1[6]*s0, f0[7]*c0 + f1[7]*s0);
      *(uint4*)&Af[((mt*4 + w)*64 + physL)*4] = o;
    }
  } else {
    // R_end[k][b] = lastw[k][0]*c255(b) + lastw[k][1]*s255(b); wave ww: kt=ww
    const int ww = w - 4;
    float g0[8], g1[8];
    #pragma unroll
    for (int j = 0; j < 8; ++j){
      int rr = 32*ww + 8*q + j;
      float2 gg = *(const float2*)(lastw + 2*rr);
      g0[j] = gg.x; g1[j] = gg.y;
    }
    #pragma unroll
    for (int nt = 0; nt < 2; ++nt){
      h2 p5 = __builtin_bit_cast(h2, phiT[255*36 + 16*nt + r]);
      const float cb = (float)p5[0], sb = (float)p5[1];
      uint4 o;
      o.x = pack2h(g0[0]*cb + g1[0]*sb, g0[1]*cb + g1[1]*sb);
      o.y = pack2h(g0[2]*cb + g1[2]*sb, g0[3]*cb + g1[3]*sb);
      o.z = pack2h(g0[4]*cb + g1[4]*sb, g0[5]*cb + g1[5]*sb);
      o.w = pack2h(g0[6]*cb + g1[6]*sb, g0[7]*cb + g1[7]*sb);
      *(uint4*)&Rf[((ww*2 + nt)*64 + physL)*4] = o;
    }
  }

  // ---- Step body: fwd consumes mid[t], phi(t+1); bwd mid[253-t], phi(254-t) ----
  auto body = [&](int t, uint4 (&Fc)[16], uint4 (&Fn)[16]){
    step_sync();       // LDS drain + raw barrier; B-stream loads stay in flight
    float vf[2][2][4]; // fwd final values (only live at t==126)

    if (w < 4){
      // prefetch fwd B for step t+1
      {
        const int soff = (t < 126) ? (t + 1) : 0;
        const uint4* bp = (const uint4*)wsBv + (size_t)soff * SITE_U4;
        #pragma unroll
        for (int d = 0; d < 2; ++d)
          #pragma unroll
          for (int kt = 0; kt < 4; ++kt)
            #pragma unroll
            for (int nb = 0; nb < 2; ++nb)
              Fn[(d*4+kt)*2+nb] = bp[(size_t)((d*4 + kt)*8 + 2*w + nb)*64 + lane];
      }
      __builtin_amdgcn_sched_barrier(0);   // pin load issue above compute
      v4f ac0[2][2] = {};   // [mt][nb], plane 0
      v4f ac1[2][2] = {};   // plane 1
      const unsigned* Ab = &Af[(t & 1) * 2048];
      #pragma unroll
      for (int kt = 0; kt < 4; ++kt){
        uint4 a0 = *(const uint4*)&Ab[((0*4 + kt)*64 + physL)*4];
        uint4 a1 = *(const uint4*)&Ab[((1*4 + kt)*64 + physL)*4];
        #pragma unroll
        for (int nb = 0; nb < 2; ++nb){
          ac0[0][nb] = mfma16h(a0, Fc[(0*4+kt)*2+nb], ac0[0][nb]);
          ac0[1][nb] = mfma16h(a1, Fc[(0*4+kt)*2+nb], ac0[1][nb]);
          ac1[0][nb] = mfma16h(a0, Fc[(1*4+kt)*2+nb], ac1[0][nb]);
          ac1[1][nb] = mfma16h(a1, Fc[(1*4+kt)*2+nb], ac1[1][nb]);
        }
      }
      if (t < 126){
        // left'[b][l]: b=16mt+4q+reg, l=32w+16nb+r -> Af[(t+1)&1], kt=w
        unsigned short* Wb = (unsigned short*)&Af[((t+1) & 1) * 2048];
        #pragma unroll
        for (int mt = 0; mt < 2; ++mt){
          uint4 phiu = *(const uint4*)&phiT[(t+1)*36 + 16*mt + 4*q];
          const unsigned pr[4] = {phiu.x, phiu.y, phiu.z, phiu.w};
          #pragma unroll
          for (int nb = 0; nb < 2; ++nb){
            const int S0 = 32*nb + 16*rh + 4*q;
            const int X  = 4*nb + 2*rh + (q >> 1);
            #pragma unroll
            for (int reg = 0; reg < 4; ++reg){
              h2 ph = __builtin_bit_cast(h2, pr[reg]);
              float v = (float)ph[0]*ac0[mt][nb][reg]
                      + (float)ph[1]*ac1[mt][nb][reg];
              Wb[((mt*4 + w)*64 + ((S0 + reg) ^ X))*8 + (r & 7)] = f16b(v);
            }
          }
        }
      } else {
        // final fwd: vf = left_128 (phi(127) applied), held in registers
        #pragma unroll
        for (int mt = 0; mt < 2; ++mt){
          uint4 phiu = *(const uint4*)&phiT[127*36 + 16*mt + 4*q];
          const unsigned pr[4] = {phiu.x, phiu.y, phiu.z, phiu.w};
          #pragma unroll
          for (int nb = 0; nb < 2; ++nb)
            #pragma unroll
            for (int reg = 0; reg < 4; ++reg){
              h2 ph = __builtin_bit_cast(h2, pr[reg]);
              vf[mt][nb][reg] = (float)ph[0]*ac0[mt][nb][reg]
                              + (float)ph[1]*ac1[mt][nb][reg];
            }
        }
      }
    } else {
      const int ww = w - 4;
      // prefetch bwd A (transposed frags) for step t+1
      {
        const int srel = (t < 126) ? (125 - t) : 0;
        const uint4* bp = (const uint4*)wsBv + TOFF_U4 + (size_t)srel * SITE_U4;
        #pragma unroll
        for (int d = 0; d < 2; ++d)
          #pragma unroll
          for (int mtl = 0; mtl < 2; ++mtl)
            #pragma unroll
            for (int kt = 0; kt < 4; ++kt)
              Fn[(d*2+mtl)*4+kt] = bp[(size_t)((d*8 + 2*ww + mtl)*4 + kt)*64 + lane];
      }
      __builtin_amdgcn_sched_barrier(0);   // pin load issue above compute
      v4f ac0[2][2] = {};   // [mtl][nt], plane 0
      v4f ac1[2][2] = {};   // plane 1
      const unsigned* Rb = &Rf[(t & 1) * 2048];
      #pragma unroll
      for (int kt = 0; kt < 4; ++kt){
        uint4 b0 = *(const uint4*)&Rb[((kt*2 + 0)*64 + physL)*4];
        uint4 b1 = *(const uint4*)&Rb[((kt*2 + 1)*64 + physL)*4];
        #pragma unroll
        for (int mtl = 0; mtl < 2; ++mtl){
          ac0[mtl][0] = mfma16h(Fc[(0*2+mtl)*4+kt], b0, ac0[mtl][0]);
          ac0[mtl][1] = mfma16h(Fc[(0*2+mtl)*4+kt], b1, ac0[mtl][1]);
          ac1[mtl][0] = mfma16h(Fc[(1*2+mtl)*4+kt], b0, ac1[mtl][0]);
          ac1[mtl][1] = mfma16h(Fc[(1*2+mtl)*4+kt], b1, ac1[mtl][1]);
        }
      }
      const int ps = 254 - t;
      if (t < 126){
        // R'[k=l][b]: l=32ww+16mtl+4q+reg, b=16nb+r -> Rf[(t+1)&1], kt=ww
        unsigned short* Wr = (unsigned short*)&Rf[((t+1) & 1) * 2048];
        #pragma unroll
        for (int nb = 0; nb < 2; ++nb){
          h2 ph = __builtin_bit_cast(h2, phiT[ps*36 + 16*nb + r]);
          const float cb = (float)ph[0], sb = (float)ph[1];
          #pragma unroll
          for (int mtl = 0; mtl < 2; ++mtl){
            const int S0 = 32*mtl + 16*(q >> 1) + r;
            const int phys = S0 ^ ((S0 >> 3) & 7);
            #pragma unroll
            for (int reg = 0; reg < 4; ++reg){
              float v = cb*ac0[mtl][nb][reg] + sb*ac1[mtl][nb][reg];
              Wr[((ww*2 + nb)*64 + phys)*8 + ((4*q + reg) & 7)] = f16b(v);
            }
          }
        }
      } else {
        // final bwd: R_127 -> Rcomb[l][b]
        #pragma unroll
        for (int nb = 0; nb < 2; ++nb){
          h2 ph = __builtin_bit_cast(h2, phiT[ps*36 + 16*nb + r]);
          const float cb = (float)ph[0], sb = (float)ph[1];
          #pragma unroll
          for (int mtl = 0; mtl < 2; ++mtl)
            #pragma unroll
            for (int reg = 0; reg < 4; ++reg){
              float v = cb*ac0[mtl][nb][reg] + sb*ac1[mtl][nb][reg];
              int l = 32*ww + 16*mtl + 4*q + reg;
              Rcomb[l*33 + 16*nb + r] = v;
            }
        }
      }
    }

    if (t == 126){
      if (tid < 32) scal[tid] = 0.0f;
      __syncthreads();   // Rcomb + scal ready (full sync fine, happens once)
      if (w < 4){
        float p[2][4] = {};
        #pragma unroll
        for (int mt = 0; mt < 2; ++mt)
          #pragma unroll
          for (int nb = 0; nb < 2; ++nb){
            const int l = 32*w + 16*nb + r;
            #pragma unroll
            for (int reg = 0; reg < 4; ++reg)
              p[mt][reg] += vf[mt][nb][reg] * Rcomb[l*33 + 16*mt + 4*q + reg];
          }
        #pragma unroll
        for (int m = 1; m < 16; m <<= 1)
          #pragma unroll
          for (int mt = 0; mt < 2; ++mt)
            #pragma unroll
            for (int reg = 0; reg < 4; ++reg)
              p[mt][reg] += __shfl_xor(p[mt][reg], m);
        if (r == 0){
          #pragma unroll
          for (int mt = 0; mt < 2; ++mt)
            #pragma unroll
            for (int reg = 0; reg < 4; ++reg)
              atomicAdd(&scal[16*mt + 4*q + reg], p[mt][reg]);
        }
      }
      __syncthreads();
      for (int t2 = tid; t2 < 320; t2 += 512){
        int bb = t2 / 10, o = t2 - bb*10;
        out[(size_t)(rowbase + bb)*10 + o] = scal[bb]*wlin[o] + blin[o];
      }
    }
  };

  #pragma unroll 1
  for (int t = 0; t < 126; t += 2){
    body(t,     B0, B1);
    body(t + 1, B1, B0);
  }
  body(126, B0, B1);
}

extern "C" void kernel_launch(void* const* d_in, const int* in_sizes, int n_in,
                              void* d_out, int out_size, void* d_ws, size_t ws_size,
                              hipStream_t stream){
  (void)in_sizes; (void)n_in; (void)out_size; (void)ws_size;
  const float* x     = (const float*)d_in[0];
  const float* first = (const float*)d_in[1];
  const float* mid   = (const float*)d_in[2];
  const float* lastw = (const float*)d_in[3];
  const float* wlin  = (const float*)d_in[4];
  const float* blin  = (const float*)d_in[5];
  float* o            = (float*)d_out;
  unsigned short* wsB = (unsigned short*)d_ws;   // 16.6 MB fp16 fragments

  hipLaunchKernelGGL(repack_mid, dim3(1016), dim3(256), 0, stream, mid, wsB);
  hipLaunchKernelGGL(mps_main,   dim3(256),  dim3(512), 0, stream,
                     x, first, wsB, lastw, wlin, blin, o);
}

// Round 9
// 262.130 us; speedup vs baseline: 1.0932x; 1.0568x over previous
//
#include <hip/hip_runtime.h>

// MPS classifier, MI355X gfx950. Round 15: RECOMBINATION of proven parts.
// r14 post-mortem: counted-wait sync (raw barrier + lgkm-only drain +
// sched_barrier pins) REGRESSED main 189->210 (pins defeat compiler
// scheduling, m141 failure mode); but r14 verified the half-size repack +
// in-WG combine (overhead 67us vs r9's 81). This round = r9's main verbatim
// (plain __syncthreads, best measured 186-192us) + r14's half repack and
// bwd srel addressing. No new mechanisms.
// Structure: 256 WGs x 512 thr, 32 rows/WG. Waves 0-3 fwd
// (left' = c*(L@M0)+s*(L@M1), state = A-op in LDS, stream = B-op regs);
// waves 4-7 bwd (R' = c*(M0@R)+s*(M1@R), state = B-op in LDS, stream =
// A-op-T regs). Middle combine in-WG: scalar[b] = sum_l L128[b,l]*R127[l,b].

typedef _Float16 v8h __attribute__((ext_vector_type(8)));
typedef _Float16 h2  __attribute__((ext_vector_type(2)));
typedef float    v4f __attribute__((ext_vector_type(4)));

#define PI_HALF 1.5707963267948966f
#define SITE_U4 4096                 // uint4 per site: 2 planes * 32 frags * 64
#define TOFF_U4 (127*4096)           // bwd (transposed) half base, in uint4

union U4H8 { uint4 u; v8h h; };

__device__ __forceinline__ v4f mfma16h(uint4 a, uint4 b, v4f c){
  U4H8 ua, ub; ua.u = a; ub.u = b;
  return __builtin_amdgcn_mfma_f32_16x16x32_f16(ua.h, ub.h, c, 0, 0, 0);
}
__device__ __forceinline__ unsigned pack2h(float lo, float hi){
  h2 p; p[0] = (_Float16)lo; p[1] = (_Float16)hi;
  return __builtin_bit_cast(unsigned, p);
}
__device__ __forceinline__ unsigned short f16b(float v){
  return __builtin_bit_cast(unsigned short, (_Float16)v);
}

// ---------------------------------------------------------------------------
// Repack mid (fp32 [254][128][2][128]) — half-size (r12/r14 verbatim).
// Blocks 0..507   (sites 0..126)  -> fwd B-op frags [site][d][kt4][nt8][64]:
//   (lane,j) = mid[site][k=32kt+8(lane>>4)+j][d][n=16nt+(lane&15)]
// Blocks 508..1015 (sites 127..253)-> bwd A-op frags at TOFF [srel][d][am8][kt4][64]:
//   (lane,j) = mid[site][m=16am+(lane&15)][d][k=32kt+8(lane>>4)+j]
// ---------------------------------------------------------------------------
__global__ __launch_bounds__(256) void repack_mid(const float* __restrict__ mid,
                                                  unsigned short* __restrict__ wsB){
  const int bid = blockIdx.x;
  if (bid < 508){
    int idx  = bid * 256 + threadIdx.x;
    int lg   = idx & 15;
    int nt   = (idx >> 4) & 7;
    int kt   = (idx >> 7) & 3;
    int d    = (idx >> 9) & 1;
    int site = idx >> 10;            // 0..126
    int q    = lg >> 2;
    int n0   = 16*nt + 4*(lg & 3);
    const float* src = mid + ((size_t)(site*128 + 32*kt + 8*q)*2 + d)*128 + n0;
    float V[8][4];
    #pragma unroll
    for (int j = 0; j < 8; ++j){
      float4 a = *(const float4*)(src + (size_t)j*256);
      V[j][0]=a.x; V[j][1]=a.y; V[j][2]=a.z; V[j][3]=a.w;
    }
    uint4* dst = (uint4*)wsB + ((((size_t)site*2 + d)*4 + kt)*8 + nt)*64
               + 16*q + 4*(lg & 3);
    #pragma unroll
    for (int t = 0; t < 4; ++t){
      uint4 o;
      o.x = pack2h(V[0][t], V[1][t]);
      o.y = pack2h(V[2][t], V[3][t]);
      o.z = pack2h(V[4][t], V[5][t]);
      o.w = pack2h(V[6][t], V[7][t]);
      dst[t] = o;
    }
  } else {
    int idx  = (bid - 508) * 256 + threadIdx.x;
    int lg   = idx & 15;
    int kt   = (idx >> 4) & 3;
    int am   = (idx >> 6) & 7;
    int d    = (idx >> 9) & 1;
    int srel = idx >> 10;            // 0..126
    int site = 127 + srel;
    int q    = lg >> 2;
    int m0   = 16*am + 4*(lg & 3);
    int k0   = 32*kt + 8*q;
    uint4* dst = (uint4*)wsB + TOFF_U4
               + ((((size_t)srel*2 + d)*8 + am)*4 + kt)*64 + 16*q + 4*(lg & 3);
    #pragma unroll
    for (int mp = 0; mp < 4; ++mp){
      const float* src = mid + ((size_t)((site*128 + m0 + mp)*2) + d)*128 + k0;
      float4 a = *(const float4*)(src);
      float4 b = *(const float4*)(src + 4);
      uint4 o;
      o.x = pack2h(a.x, a.y);
      o.y = pack2h(a.z, a.w);
      o.z = pack2h(b.x, b.y);
      o.w = pack2h(b.z, b.w);
      dst[mp] = o;
    }
  }
}

// ---------------------------------------------------------------------------
// Main kernel (r9 structure, plain __syncthreads). 256 WGs x 512 threads.
// Slot swizzle: phys = S ^ ((S>>3)&7) on write and read.
// ---------------------------------------------------------------------------
__global__ __launch_bounds__(512, 2) void mps_main(
    const float* __restrict__ x,               // [8192][256]
    const float* __restrict__ first,           // [2][128]
    const unsigned short* __restrict__ wsBv,   // repacked mid (both halves)
    const float* __restrict__ lastw,           // [128][2]
    const float* __restrict__ wlin,            // [10]
    const float* __restrict__ blin,            // [10]
    float* __restrict__ out)                   // [8192][10]
{
  __shared__ unsigned phiT[256*36];        // 36 KB
  __shared__ unsigned Af[2*2*4*64*4];      // 16 KB  [buf][mt][kt][slot][word]
  __shared__ unsigned Rf[2*4*2*64*4];      // 16 KB  [buf][kt][nt][slot][word]
  __shared__ float Rcomb[128*33];          // 16.9 KB
  __shared__ float scal[32];

  const int tid  = threadIdx.x;
  const int gblk = blockIdx.x;
  const int w    = tid >> 6;               // 0..3 fwd, 4..7 bwd
  const int lane = tid & 63;
  const int r    = lane & 15;
  const int q    = lane >> 4;
  const int rh   = r >> 3;
  const int rowbase = gblk * 32;
  const int physL = lane ^ ((lane >> 3) & 7);

  // ---- Phase 1: feature map -> packed f16 (cos,sin) table ----
  {
    const int row = tid >> 4;              // 0..31
    const int c0  = (tid & 15) * 16;       // 16-site chunk
    const float4* xp = (const float4*)(x + (size_t)(rowbase + row) * 256 + c0);
    float xv[16];
    float vmin = 3.0e38f, vmax = -3.0e38f;
    #pragma unroll
    for (int c = 0; c < 4; ++c){
      float4 u = xp[c];
      xv[c*4+0] = u.x; xv[c*4+1] = u.y; xv[c*4+2] = u.z; xv[c*4+3] = u.w;
      vmin = fminf(vmin, fminf(fminf(u.x,u.y), fminf(u.z,u.w)));
      vmax = fmaxf(vmax, fmaxf(fmaxf(u.x,u.y), fmaxf(u.z,u.w)));
    }
    #pragma unroll
    for (int m = 1; m < 16; m <<= 1){
      vmin = fminf(vmin, __shfl_xor(vmin, m));
      vmax = fmaxf(vmax, __shfl_xor(vmax, m));
    }
    const float sc = PI_HALF / (vmax - vmin + 1e-6f);
    #pragma unroll
    for (int j = 0; j < 16; ++j){
      float a = (xv[j] - vmin) * sc;
      phiT[(c0 + j)*36 + row] = pack2h(__cosf(a), __sinf(a));
    }
  }
  __syncthreads();

  // ---- Initial B prefetch (step 0): fwd site 0, bwd srel 126 (site 253) ----
  uint4 B0[16], B1[16];
  if (w < 4){
    const uint4* bp = (const uint4*)wsBv;
    #pragma unroll
    for (int d = 0; d < 2; ++d)
      #pragma unroll
      for (int kt = 0; kt < 4; ++kt)
        #pragma unroll
        for (int nb = 0; nb < 2; ++nb)
          B0[(d*4+kt)*2+nb] = bp[(size_t)((d*4 + kt)*8 + 2*w + nb)*64 + lane];
  } else {
    const int ww = w - 4;
    const uint4* bp = (const uint4*)wsBv + TOFF_U4 + (size_t)126 * SITE_U4;
    #pragma unroll
    for (int d = 0; d < 2; ++d)
      #pragma unroll
      for (int mtl = 0; mtl < 2; ++mtl)
        #pragma unroll
        for (int kt = 0; kt < 4; ++kt)
          B0[(d*2+mtl)*4+kt] = bp[(size_t)((d*8 + 2*ww + mtl)*4 + kt)*64 + lane];
  }

  // ---- State init (buf 0) ----
  if (w < 4){
    // left_1[b][l] = c0(b)*first[0][l] + s0(b)*first[1][l]; wave w: kt=w
    float f0[8], f1[8];
    #pragma unroll
    for (int j = 0; j < 8; ++j){
      int l = 32*w + 8*q + j;
      f0[j] = first[l]; f1[j] = first[128 + l];
    }
    #pragma unroll
    for (int mt = 0; mt < 2; ++mt){
      h2 ph0 = __builtin_bit_cast(h2, phiT[0*36 + 16*mt + r]);
      const float c0 = (float)ph0[0], s0 = (float)ph0[1];
      uint4 o;
      o.x = pack2h(f0[0]*c0 + f1[0]*s0, f0[1]*c0 + f1[1]*s0);
      o.y = pack2h(f0[2]*c0 + f1[2]*s0, f0[3]*c0 + f1[3]*s0);
      o.z = pack2h(f0[4]*c0 + f1[4]*s0, f0[5]*c0 + f1[5]*s0);
      o.w = pack2h(f0[6]*c0 + f1[6]*s0, f0[7]*c0 + f1[7]*s0);
      *(uint4*)&Af[((mt*4 + w)*64 + physL)*4] = o;
    }
  } else {
    // R_end[k][b] = lastw[k][0]*c255(b) + lastw[k][1]*s255(b); wave ww: kt=ww
    const int ww = w - 4;
    float g0[8], g1[8];
    #pragma unroll
    for (int j = 0; j < 8; ++j){
      int rr = 32*ww + 8*q + j;
      float2 gg = *(const float2*)(lastw + 2*rr);
      g0[j] = gg.x; g1[j] = gg.y;
    }
    #pragma unroll
    for (int nt = 0; nt < 2; ++nt){
      h2 p5 = __builtin_bit_cast(h2, phiT[255*36 + 16*nt + r]);
      const float cb = (float)p5[0], sb = (float)p5[1];
      uint4 o;
      o.x = pack2h(g0[0]*cb + g1[0]*sb, g0[1]*cb + g1[1]*sb);
      o.y = pack2h(g0[2]*cb + g1[2]*sb, g0[3]*cb + g1[3]*sb);
      o.z = pack2h(g0[4]*cb + g1[4]*sb, g0[5]*cb + g1[5]*sb);
      o.w = pack2h(g0[6]*cb + g1[6]*sb, g0[7]*cb + g1[7]*sb);
      *(uint4*)&Rf[((ww*2 + nt)*64 + physL)*4] = o;
    }
  }

  // ---- Step body: fwd consumes mid[t], phi(t+1); bwd mid[253-t], phi(254-t) ----
  auto body = [&](int t, uint4 (&Fc)[16], uint4 (&Fn)[16]){
    __syncthreads();   // state frags for step t visible; prev-buf reads done
    float vf[2][2][4]; // fwd final values (only live at t==126)

    if (w < 4){
      // prefetch fwd B for step t+1
      {
        const int soff = (t < 126) ? (t + 1) : 0;
        const uint4* bp = (const uint4*)wsBv + (size_t)soff * SITE_U4;
        #pragma unroll
        for (int d = 0; d < 2; ++d)
          #pragma unroll
          for (int kt = 0; kt < 4; ++kt)
            #pragma unroll
            for (int nb = 0; nb < 2; ++nb)
              Fn[(d*4+kt)*2+nb] = bp[(size_t)((d*4 + kt)*8 + 2*w + nb)*64 + lane];
      }
      v4f ac0[2][2] = {};   // [mt][nb], plane 0
      v4f ac1[2][2] = {};   // plane 1
      const unsigned* Ab = &Af[(t & 1) * 2048];
      #pragma unroll
      for (int kt = 0; kt < 4; ++kt){
        uint4 a0 = *(const uint4*)&Ab[((0*4 + kt)*64 + physL)*4];
        uint4 a1 = *(const uint4*)&Ab[((1*4 + kt)*64 + physL)*4];
        #pragma unroll
        for (int nb = 0; nb < 2; ++nb){
          ac0[0][nb] = mfma16h(a0, Fc[(0*4+kt)*2+nb], ac0[0][nb]);
          ac0[1][nb] = mfma16h(a1, Fc[(0*4+kt)*2+nb], ac0[1][nb]);
          ac1[0][nb] = mfma16h(a0, Fc[(1*4+kt)*2+nb], ac1[0][nb]);
          ac1[1][nb] = mfma16h(a1, Fc[(1*4+kt)*2+nb], ac1[1][nb]);
        }
      }
      if (t < 126){
        // left'[b][l]: b=16mt+4q+reg, l=32w+16nb+r -> Af[(t+1)&1], kt=w
        unsigned short* Wb = (unsigned short*)&Af[((t+1) & 1) * 2048];
        #pragma unroll
        for (int mt = 0; mt < 2; ++mt){
          uint4 phiu = *(const uint4*)&phiT[(t+1)*36 + 16*mt + 4*q];
          const unsigned pr[4] = {phiu.x, phiu.y, phiu.z, phiu.w};
          #pragma unroll
          for (int nb = 0; nb < 2; ++nb){
            const int S0 = 32*nb + 16*rh + 4*q;
            const int X  = 4*nb + 2*rh + (q >> 1);
            #pragma unroll
            for (int reg = 0; reg < 4; ++reg){
              h2 ph = __builtin_bit_cast(h2, pr[reg]);
              float v = (float)ph[0]*ac0[mt][nb][reg]
                      + (float)ph[1]*ac1[mt][nb][reg];
              Wb[((mt*4 + w)*64 + ((S0 + reg) ^ X))*8 + (r & 7)] = f16b(v);
            }
          }
        }
      } else {
        // final fwd: vf = left_128 (phi(127) applied), held in registers
        #pragma unroll
        for (int mt = 0; mt < 2; ++mt){
          uint4 phiu = *(const uint4*)&phiT[127*36 + 16*mt + 4*q];
          const unsigned pr[4] = {phiu.x, phiu.y, phiu.z, phiu.w};
          #pragma unroll
          for (int nb = 0; nb < 2; ++nb)
            #pragma unroll
            for (int reg = 0; reg < 4; ++reg){
              h2 ph = __builtin_bit_cast(h2, pr[reg]);
              vf[mt][nb][reg] = (float)ph[0]*ac0[mt][nb][reg]
                              + (float)ph[1]*ac1[mt][nb][reg];
            }
        }
      }
    } else {
      const int ww = w - 4;
      // prefetch bwd A (transposed frags) for step t+1
      {
        const int srel = (t < 126) ? (125 - t) : 0;
        const uint4* bp = (const uint4*)wsBv + TOFF_U4 + (size_t)srel * SITE_U4;
        #pragma unroll
        for (int d = 0; d < 2; ++d)
          #pragma unroll
          for (int mtl = 0; mtl < 2; ++mtl)
            #pragma unroll
            for (int kt = 0; kt < 4; ++kt)
              Fn[(d*2+mtl)*4+kt] = bp[(size_t)((d*8 + 2*ww + mtl)*4 + kt)*64 + lane];
      }
      v4f ac0[2][2] = {};   // [mtl][nt], plane 0
      v4f ac1[2][2] = {};   // plane 1
      const unsigned* Rb = &Rf[(t & 1) * 2048];
      #pragma unroll
      for (int kt = 0; kt < 4; ++kt){
        uint4 b0 = *(const uint4*)&Rb[((kt*2 + 0)*64 + physL)*4];
        uint4 b1 = *(const uint4*)&Rb[((kt*2 + 1)*64 + physL)*4];
        #pragma unroll
        for (int mtl = 0; mtl < 2; ++mtl){
          ac0[mtl][0] = mfma16h(Fc[(0*2+mtl)*4+kt], b0, ac0[mtl][0]);
          ac0[mtl][1] = mfma16h(Fc[(0*2+mtl)*4+kt], b1, ac0[mtl][1]);
          ac1[mtl][0] = mfma16h(Fc[(1*2+mtl)*4+kt], b0, ac1[mtl][0]);
          ac1[mtl][1] = mfma16h(Fc[(1*2+mtl)*4+kt], b1, ac1[mtl][1]);
        }
      }
      const int ps = 254 - t;
      if (t < 126){
        // R'[k=l][b]: l=32ww+16mtl+4q+reg, b=16nb+r -> Rf[(t+1)&1], kt=ww
        unsigned short* Wr = (unsigned short*)&Rf[((t+1) & 1) * 2048];
        #pragma unroll
        for (int nb = 0; nb < 2; ++nb){
          h2 ph = __builtin_bit_cast(h2, phiT[ps*36 + 16*nb + r]);
          const float cb = (float)ph[0], sb = (float)ph[1];
          #pragma unroll
          for (int mtl = 0; mtl < 2; ++mtl){
            const int S0 = 32*mtl + 16*(q >> 1) + r;
            const int phys = S0 ^ ((S0 >> 3) & 7);
            #pragma unroll
            for (int reg = 0; reg < 4; ++reg){
              float v = cb*ac0[mtl][nb][reg] + sb*ac1[mtl][nb][reg];
              Wr[((ww*2 + nb)*64 + phys)*8 + ((4*q + reg) & 7)] = f16b(v);
            }
          }
        }
      } else {
        // final bwd: R_127 -> Rcomb[l][b]
        #pragma unroll
        for (int nb = 0; nb < 2; ++nb){
          h2 ph = __builtin_bit_cast(h2, phiT[ps*36 + 16*nb + r]);
          const float cb = (float)ph[0], sb = (float)ph[1];
          #pragma unroll
          for (int mtl = 0; mtl < 2; ++mtl)
            #pragma unroll
            for (int reg = 0; reg < 4; ++reg){
              float v = cb*ac0[mtl][nb][reg] + sb*ac1[mtl][nb][reg];
              int l = 32*ww + 16*mtl + 4*q + reg;
              Rcomb[l*33 + 16*nb + r] = v;
            }
        }
      }
    }

    if (t == 126){
      if (tid < 32) scal[tid] = 0.0f;
      __syncthreads();   // Rcomb + scal ready
      if (w < 4){
        float p[2][4] = {};
        #pragma unroll
        for (int mt = 0; mt < 2; ++mt)
          #pragma unroll
          for (int nb = 0; nb < 2; ++nb){
            const int l = 32*w + 16*nb + r;
            #pragma unroll
            for (int reg = 0; reg < 4; ++reg)
              p[mt][reg] += vf[mt][nb][reg] * Rcomb[l*33 + 16*mt + 4*q + reg];
          }
        #pragma unroll
        for (int m = 1; m < 16; m <<= 1)
          #pragma unroll
          for (int mt = 0; mt < 2; ++mt)
            #pragma unroll
            for (int reg = 0; reg < 4; ++reg)
              p[mt][reg] += __shfl_xor(p[mt][reg], m);
        if (r == 0){
          #pragma unroll
          for (int mt = 0; mt < 2; ++mt)
            #pragma unroll
            for (int reg = 0; reg < 4; ++reg)
              atomicAdd(&scal[16*mt + 4*q + reg], p[mt][reg]);
        }
      }
      __syncthreads();
      for (int t2 = tid; t2 < 320; t2 += 512){
        int bb = t2 / 10, o = t2 - bb*10;
        out[(size_t)(rowbase + bb)*10 + o] = scal[bb]*wlin[o] + blin[o];
      }
    }
  };

  #pragma unroll 1
  for (int t = 0; t < 126; t += 2){
    body(t,     B0, B1);
    body(t + 1, B1, B0);
  }
  body(126, B0, B1);
}

extern "C" void kernel_launch(void* const* d_in, const int* in_sizes, int n_in,
                              void* d_out, int out_size, void* d_ws, size_t ws_size,
                              hipStream_t stream){
  (void)in_sizes; (void)n_in; (void)out_size; (void)ws_size;
  const float* x     = (const float*)d_in[0];
  const float* first = (const float*)d_in[1];
  const float* mid   = (const float*)d_in[2];
  const float* lastw = (const float*)d_in[3];
  const float* wlin  = (const float*)d_in[4];
  const float* blin  = (const float*)d_in[5];
  float* o            = (float*)d_out;
  unsigned short* wsB = (unsigned short*)d_ws;   // 16.6 MB fp16 fragments

  hipLaunchKernelGGL(repack_mid, dim3(1016), dim3(256), 0, stream, mid, wsB);
  hipLaunchKernelGGL(mps_main,   dim3(256),  dim3(512), 0, stream,
                     x, first, wsB, lastw, wlin, blin, o);
}